// Round 4
// baseline (95.281 us; speedup 1.0000x reference)
//
#include <hip/hip_runtime.h>
#include <math.h>

#define HAND_PARAM_DIM 32
#define INF_DIST 1000000.0f
#define EPS 1e-8f
#define NROW 64        // B*S
#define HW_N 65536
#define NV 778
#define NMESH 1556
#define K_SEL 1024u
#define HALF_BITS  0x3F000000u  // bits of 0.5f
#define GUESS_BITS 0x3F733333u  // bits of 0.95f (speculative collect threshold)
#define CAND_CAP 4096
#define CHUNK_CAP 1024
#define FIX_SCALE 4294967296.0  // 2^32 fixed-point scale

// ---- workspace layout (bytes) ----
// cand[row] doubles as the selected list: sel_fin loads a row's candidates to
// LDS, then rewrites only its own row -> no cross-block hazard.
#define OFF_CAND 0u             // 64*4096*8  = 2097152
#define OFF_MESH 2097152u       // 64*1556*16 = 1593344
#define OFF_CTR  3690496u       // u32 words: [0:64) ccount, [64:128) dcount,
                                // [128:192) rowbad, [192:194) gsum(u64), [194] gcnt, [195] done
#define CTR_WORDS 196

typedef unsigned long long u64;

// ---------------------------------------------------------------------------
// Kernel 0: zero the per-launch counters (must be re-zeroed every call).
// ---------------------------------------------------------------------------
__global__ void __launch_bounds__(256) zero_kernel(unsigned* __restrict__ ctr) {
    int t = threadIdx.x;
    if (t < CTR_WORDS) ctr[t] = 0u;
}

// ---------------------------------------------------------------------------
// Kernel 1: blocks 0..1023 = speculative collect (1 pass over mask);
//           blocks 1024..1151 = MANO mesh points (independent work).
// ---------------------------------------------------------------------------
__global__ void __launch_bounds__(256) combo_kernel(
    const float* __restrict__ mask, const int* __restrict__ hv,
    u64* __restrict__ cand, unsigned* __restrict__ ccount, unsigned* __restrict__ rowbad,
    const float* __restrict__ hp,
    const float* __restrict__ vtl, const float* __restrict__ vtr,
    const float* __restrict__ sdl, const float* __restrict__ sdr,
    const float* __restrict__ pdl, const float* __restrict__ pdr,
    float4* __restrict__ meshQ)
{
    __shared__ u64 loc[CHUNK_CAP];
    __shared__ unsigned nc, base;
    int blk = blockIdx.x;
    int t = threadIdx.x;

    if (blk < 1024) {
        // ---- speculative collect: all elements with bits >= GUESS_BITS ----
        int row = blk >> 4, chunk = blk & 15;
        if (!(hv[row*2] | hv[row*2+1])) return;
        if (t == 0) nc = 0u;
        __syncthreads();
        const float4* m4 = (const float4*)(mask + (size_t)row * HW_N + chunk * 4096);
#pragma unroll
        for (int k = 0; k < 4; k++) {
            float4 v = m4[k*256 + t];
            unsigned e0 = (unsigned)(chunk*4096 + k*1024 + t*4);
            unsigned u;
            u = __float_as_uint(v.x);
            if (u >= GUESS_BITS) { unsigned p = atomicAdd(&nc,1u); if (p < CHUNK_CAP) loc[p] = ((u64)u<<32)|(e0+0u); }
            u = __float_as_uint(v.y);
            if (u >= GUESS_BITS) { unsigned p = atomicAdd(&nc,1u); if (p < CHUNK_CAP) loc[p] = ((u64)u<<32)|(e0+1u); }
            u = __float_as_uint(v.z);
            if (u >= GUESS_BITS) { unsigned p = atomicAdd(&nc,1u); if (p < CHUNK_CAP) loc[p] = ((u64)u<<32)|(e0+2u); }
            u = __float_as_uint(v.w);
            if (u >= GUESS_BITS) { unsigned p = atomicAdd(&nc,1u); if (p < CHUNK_CAP) loc[p] = ((u64)u<<32)|(e0+3u); }
        }
        __syncthreads();
        unsigned n = (nc < CHUNK_CAP) ? nc : CHUNK_CAP;
        if (t == 0) {
            if (nc > CHUNK_CAP) rowbad[row] = 1u;   // truncated -> exact fallback
            base = atomicAdd(&ccount[row], n);
        }
        __syncthreads();
        unsigned b = base;
        for (unsigned i = t; i < n; i += 256) {
            unsigned p = b + i;
            if (p < CAND_CAP) cand[(size_t)row * CAND_CAP + p] = loc[i];
        }
        return;
    }

    // ---- mesh points ----
    int mb   = blk - 1024;
    int row  = mb >> 1;
    int hand = mb & 1;
    const float* p = hp + row * (2 * HAND_PARAM_DIM) + hand * HAND_PARAM_DIM;
    int valid = hv[row * 2 + hand];

    const float* vt = hand ? vtr : vtl;
    const float* sd = hand ? sdr : sdl;
    const float* pd = hand ? pdr : pdl;

    float tx = p[0], ty = p[1], tz = p[2];
    float q0 = p[3], q1 = p[4], q2 = p[5], q3 = p[6];
    float qn = sqrtf(q0*q0 + q1*q1 + q2*q2 + q3*q3 + EPS);
    float inv = 1.0f / fmaxf(qn, EPS);
    q0 *= inv; q1 *= inv; q2 *= inv; q3 *= inv;
    float sgn = (q0 < 0.0f) ? -1.0f : 1.0f;
    q0 *= sgn; q1 *= sgn; q2 *= sgn; q3 *= sgn;
    float sin_half = sqrtf(q1*q1 + q2*q2 + q3*q3 + EPS);
    float w_safe = fminf(fmaxf(q0, -1.0f + EPS), 1.0f - EPS);
    float ang2 = 2.0f * atan2f(sin_half, w_safe);
    float factor = (sin_half < 1e-6f) ? 2.0f : ang2 / fmaxf(sin_half, EPS);
    float rx = q1 * factor, ry = q2 * factor, rz = q3 * factor;
    float ang = sqrtf(rx*rx + ry*ry + rz*rz + EPS);
    float iang = 1.0f / ang;
    float ax = rx * iang, ay = ry * iang, az = rz * iang;
    float c = cosf(ang), s = sinf(ang), omc = 1.0f - c;

    float pose[15], betas[10];
#pragma unroll
    for (int k = 0; k < 15; k++) pose[k] = p[7 + k];
#pragma unroll
    for (int k = 0; k < 10; k++) betas[k] = p[22 + k];

    for (int v = t; v < NV; v += 256) {
        float px = vt[v*3+0], py = vt[v*3+1], pz = vt[v*3+2];
        const float* sdv = sd + v * 30;
#pragma unroll
        for (int k = 0; k < 10; k++) {
            px = fmaf(sdv[k],      betas[k], px);
            py = fmaf(sdv[10 + k], betas[k], py);
            pz = fmaf(sdv[20 + k], betas[k], pz);
        }
        const float* pdv = pd + v * 45;
#pragma unroll
        for (int k = 0; k < 15; k++) {
            px = fmaf(pdv[k],      pose[k], px);
            py = fmaf(pdv[15 + k], pose[k], py);
            pz = fmaf(pdv[30 + k], pose[k], pz);
        }
        float cx = ay * pz - az * py;
        float cy = az * px - ax * pz;
        float cz = ax * py - ay * px;
        float kdv = ax * px + ay * py + az * pz;
        float ox = px * c + cx * s + ax * kdv * omc + tx;
        float oy = py * c + cy * s + ay * kdv * omc + ty;
        float oz = pz * c + cz * s + az * kdv * omc + tz;
        if (!valid) { ox = INF_DIST; oy = INF_DIST; oz = INF_DIST; }
        float sb = fmaf(ox, ox, fmaf(oy, oy, oz * oz));
        meshQ[row * NMESH + hand * NV + v] = make_float4(ox, oy, oz, sb);
    }
}

// ---------------------------------------------------------------------------
// Kernel 2: per-row exact top-1024. Fast path: 4-phase byte radix over the
// LDS candidate set (valid when 1024 <= ccount <= CAND_CAP and not truncated).
// Fallback path (same code, global reads over the whole row) is exact for any
// non-negative mask. Selected (val,idx) pairs overwrite cand[row][0..1023].
// ---------------------------------------------------------------------------
__global__ void __launch_bounds__(256) sel_fin_kernel(
    const float* __restrict__ mask, const int* __restrict__ hv,
    u64* __restrict__ cand, const unsigned* __restrict__ ccount,
    const unsigned* __restrict__ rowbad, unsigned* __restrict__ dcount)
{
    __shared__ unsigned cval[CAND_CAP], cidx[CAND_CAP];   // 32 KB
    __shared__ unsigned h[256], seg[256];
    __shared__ unsigned sbin, sRn;
    __shared__ unsigned tlist[256];
    __shared__ unsigned tn, ns, scut;
    int row = blockIdx.x, t = threadIdx.x;
    if (!(hv[row*2] | hv[row*2+1])) return;       // dcount stays 0

    unsigned cnt = ccount[row];
    bool ok = (cnt >= K_SEL) && (cnt <= CAND_CAP) && (rowbad[row] == 0u);
    const float* mrow = mask + (size_t)row * HW_N;
    unsigned M = ok ? cnt : (unsigned)HW_N;

    if (ok) {
        for (unsigned i = t; i < cnt; i += 256) {
            u64 c = cand[(size_t)row * CAND_CAP + i];
            cval[i] = (unsigned)(c >> 32); cidx[i] = (unsigned)c;
        }
    }
    if (t == 0) { tn = 0u; ns = 0u; }
    __syncthreads();

    unsigned pfx = 0u, R = K_SEL;
    for (int ph = 0; ph < 4; ph++) {
        int sh = 24 - 8 * ph;
        unsigned pm = (ph == 0) ? 0u : (0xFFFFFFFFu << (sh + 8));
        h[t] = 0u;
        __syncthreads();
        for (unsigned i = t; i < M; i += 256) {
            unsigned u = ok ? cval[i] : __float_as_uint(mrow[i]);
            if ((u & pm) == pfx) atomicAdd(&h[(u >> sh) & 0xFFu], 1u);
        }
        __syncthreads();
        seg[t] = h[t];
        __syncthreads();
        for (int off = 1; off < 256; off <<= 1) {     // inclusive suffix scan
            unsigned v = (t + off < 256) ? seg[t + off] : 0u;
            __syncthreads(); seg[t] += v; __syncthreads();
        }
        unsigned excl = (t < 255) ? seg[t + 1] : 0u;
        if (excl < R && R <= seg[t]) { sbin = (unsigned)t; sRn = R - excl; }
        __syncthreads();
        pfx |= sbin << sh;
        R = sRn;
        __syncthreads();
    }
    unsigned T = pfx;
    // ties at exact value T -> R-th smallest index is the cut
    for (unsigned i = t; i < M; i += 256) {
        unsigned u = ok ? cval[i] : __float_as_uint(mrow[i]);
        if (u == T) {
            unsigned p = atomicAdd(&tn, 1u);
            if (p < 256u) tlist[p] = ok ? cidx[i] : i;
        }
    }
    __syncthreads();
    if (t == 0) {
        unsigned n2 = (tn < 256u) ? tn : 256u;
        for (unsigned a = 1; a < n2; a++) {
            unsigned key = tlist[a]; int b = (int)a - 1;
            while (b >= 0 && tlist[b] > key) { tlist[b+1] = tlist[b]; b--; }
            tlist[b+1] = key;
        }
        unsigned r = R;
        if (r > n2) r = n2;
        if (r < 1u) r = 1u;
        scut = (n2 > 0u) ? tlist[r - 1] : 0u;
    }
    __syncthreads();
    unsigned cut = scut;
    // write the selected set (order-free; downstream sum is order-invariant)
    for (unsigned i = t; i < M; i += 256) {
        unsigned u  = ok ? cval[i] : __float_as_uint(mrow[i]);
        unsigned id = ok ? cidx[i] : i;
        if (u > T || (u == T && id <= cut)) {
            unsigned p = atomicAdd(&ns, 1u);
            if (p < K_SEL) cand[(size_t)row * CAND_CAP + p] = ((u64)u << 32) | id;
        }
    }
    __syncthreads();
    if (t == 0) dcount[row] = (ns < K_SEL) ? ns : K_SEL;
}

// ---------------------------------------------------------------------------
// Kernel 3: NN distance + global fixed-point reduce + last-block finalize.
// 1024 blocks = (row, 64-sample chunk); 256 thr = 64 lanes x 4 mesh-quarters.
// ---------------------------------------------------------------------------
__global__ void __launch_bounds__(256) dist_kernel(
    const float4* __restrict__ meshQ, const float* __restrict__ means,
    const u64* __restrict__ cand, const unsigned* __restrict__ dcount,
    u64* __restrict__ gsum, unsigned* __restrict__ gcnt, unsigned* __restrict__ done,
    float* __restrict__ out)
{
    __shared__ float4 mq[NMESH];
    __shared__ float red[256];
    __shared__ long long redl[256];
    __shared__ unsigned redc[256];
    int blk = blockIdx.x;
    int row = blk >> 4, c = blk & 15;
    int t = threadIdx.x;
    int s = t & 63, q = t >> 6;

    unsigned n = dcount[row]; if (n > K_SEL) n = K_SEL;
    if (n) {
        for (int i = t; i < NMESH; i += 256) mq[i] = meshQ[row * NMESH + i];
    }
    long long accl = 0; unsigned accc = 0;
    __syncthreads();
    if (n) {
        unsigned g = (unsigned)(c * 64 + s);
        bool act = false;
        float sx = 0.f, sy = 0.f, sz = 0.f;
        if (g < n) {
            u64 e = cand[(size_t)row * CAND_CAP + g];
            unsigned uval = (unsigned)(e >> 32);
            unsigned idx  = (unsigned)e;
            if (uval > HALF_BITS) {
                act = true;
                const float* gm = means + ((size_t)row * HW_N + idx) * 3;
                sx = gm[0]; sy = gm[1]; sz = gm[2];
            }
        }
        float m0 = 3.4e38f, m1 = 3.4e38f, m2 = 3.4e38f, m3 = 3.4e38f;
        if (act) {
            int p = q;
            for (int j = 0; j < 97; j++) {
                float4 a0 = mq[p], a1 = mq[p+4], a2 = mq[p+8], a3 = mq[p+12];
                float d0 = fmaf(sx, a0.x, fmaf(sy, a0.y, sz * a0.z));
                float d1 = fmaf(sx, a1.x, fmaf(sy, a1.y, sz * a1.z));
                float d2 = fmaf(sx, a2.x, fmaf(sy, a2.y, sz * a2.z));
                float d3 = fmaf(sx, a3.x, fmaf(sy, a3.y, sz * a3.z));
                m0 = fminf(m0, fmaf(-2.0f, d0, a0.w));
                m1 = fminf(m1, fmaf(-2.0f, d1, a1.w));
                m2 = fminf(m2, fmaf(-2.0f, d2, a2.w));
                m3 = fminf(m3, fmaf(-2.0f, d3, a3.w));
                p += 16;
            }
            {   // tail point 388: p = q + 1552
                float4 a = mq[q + 1552];
                float dd = fmaf(sx, a.x, fmaf(sy, a.y, sz * a.z));
                m0 = fminf(m0, fmaf(-2.0f, dd, a.w));
            }
        }
        red[t] = fminf(fminf(m0, m1), fminf(m2, m3));
        __syncthreads();
        if (q == 0 && act) {
            float mn = fminf(fminf(red[s], red[s+64]), fminf(red[s+128], red[s+192]));
            float sa = fmaf(sx, sx, fmaf(sy, sy, sz * sz));
            float d2 = fmaxf(mn + sa, 0.0f);
            accl = (long long)((double)d2 * FIX_SCALE);
            accc = 1u;
        }
        __syncthreads();
    }
    redl[t] = accl; redc[t] = accc;
    __syncthreads();
    for (int off = 128; off > 0; off >>= 1) {
        if (t < off) { redl[t] += redl[t+off]; redc[t] += redc[t+off]; }
        __syncthreads();
    }
    if (t == 0) {
        atomicAdd(gsum, (u64)redl[0]);
        atomicAdd(gcnt, redc[0]);
        __threadfence();
        unsigned tk = atomicAdd(done, 1u);
        if (tk == 1023u) {                      // last block finalizes
            u64 sbits = atomicAdd(gsum, 0ull);
            unsigned cc = atomicAdd(gcnt, 0u);
            double sum = (double)(long long)sbits / FIX_SCALE;
            out[0] = (float)(sum / (double)(cc ? cc : 1u));
        }
    }
}

extern "C" void kernel_launch(void* const* d_in, const int* in_sizes, int n_in,
                              void* d_out, int out_size, void* d_ws, size_t ws_size,
                              hipStream_t stream) {
    const float* hp    = (const float*)d_in[0];
    const float* means = (const float*)d_in[1];
    const float* mask  = (const float*)d_in[2];
    const int*   hv    = (const int*)  d_in[3];
    const float* vtl   = (const float*)d_in[4];
    const float* vtr   = (const float*)d_in[5];
    const float* sdl   = (const float*)d_in[6];
    const float* sdr   = (const float*)d_in[7];
    const float* pdl   = (const float*)d_in[8];
    const float* pdr   = (const float*)d_in[9];
    float* out = (float*)d_out;

    char* ws = (char*)d_ws;
    u64*      cand   = (u64*)(ws + OFF_CAND);
    float4*   meshQ  = (float4*)(ws + OFF_MESH);
    unsigned* ctr    = (unsigned*)(ws + OFF_CTR);
    unsigned* ccount = ctr;            // [0:64)
    unsigned* dcount = ctr + 64;       // [64:128)
    unsigned* rowbad = ctr + 128;      // [128:192)
    u64*      gsum   = (u64*)(ctr + 192);
    unsigned* gcnt   = ctr + 194;
    unsigned* done   = ctr + 195;

    zero_kernel<<<1, 256, 0, stream>>>(ctr);
    combo_kernel<<<1024 + 128, 256, 0, stream>>>(mask, hv, cand, ccount, rowbad,
                                                 hp, vtl, vtr, sdl, sdr, pdl, pdr, meshQ);
    sel_fin_kernel<<<NROW, 256, 0, stream>>>(mask, hv, cand, ccount, rowbad, dcount);
    dist_kernel<<<NROW * 16, 256, 0, stream>>>(meshQ, means, cand, dcount,
                                               gsum, gcnt, done, out);
}